// Round 14
// baseline (230.744 us; speedup 1.0000x reference)
//
#include <hip/hip_runtime.h>
#include <hip/hip_fp16.h>
#include <math.h>

#define BLK 256

// ---------------------------------------------------------------------------
// GCNPolicyNetwork: 3-layer improved-GCN + masked softmax + mean-pool value.
// Round 14: k_agg2 address-count halving. Audit: addresses/edge is 1 for
// k_agg1 (8B xs), 1 for k_agg3 (4B scalar), 4 for k_agg2 (32B split over
// 4 lanes x 8B). k_agg2 now uses 2 lanes/node x 16B uint4 loads (2 addr/edge,
// 6.4M vs 12.8M) - the clean discriminator between address-throughput-bound
// and latency-bound gathers. Dual-node kept; 128-thread blocks keep grid=782.
// All else unchanged from R13 (linear node order per R10; x8-pad dummy srcs).
// ---------------------------------------------------------------------------

#define BSH 8                    // 256 nodes per bucket
#define NB 512                   // bucket-array size (nbuck=391 <= 512)
#define CAP 10240                // packed[] capacity per bucket (mean ~8184)
#define SCAP 12288               // srcs[] capacity per bucket (CAP + 8*256 pad)
#define EB 8192                  // edges per binning block
#define BINTH 1024               // k_bin block size
#define AGB 128                  // k_agg2 block size (2 lanes/node, dual-node)

// ---- fp16 payload helpers ----
__device__ inline float4 load_h4(const __half* base, int node, int sub) {
    const uint2* p = reinterpret_cast<const uint2*>(base + ((size_t)node << 4)) + sub;
    uint2 u = *p;
    union { unsigned u; __half2 h; } a, b;
    a.u = u.x; b.u = u.y;
    float2 fa = __half22float2(a.h), fb = __half22float2(b.h);
    return make_float4(fa.x, fa.y, fb.x, fb.y);
}

// 16B load: 8 consecutive fp16 features [sub*8, sub*8+8) of one node
__device__ inline void load_h8(const __half* base, int node, int sub,
                               float4& lo, float4& hi) {
    const uint4* p = reinterpret_cast<const uint4*>(base + ((size_t)node << 4)) + sub;
    uint4 u = *p;
    union { unsigned u; __half2 h; } a, b, c, d;
    a.u = u.x; b.u = u.y; c.u = u.z; d.u = u.w;
    float2 fa = __half22float2(a.h), fb = __half22float2(b.h);
    float2 fc = __half22float2(c.h), fd = __half22float2(d.h);
    lo = make_float4(fa.x, fa.y, fb.x, fb.y);
    hi = make_float4(fc.x, fc.y, fd.x, fd.y);
}

__device__ inline void store_h4(__half* base, int node, int sub, float4 v) {
    union { unsigned u; __half2 h; } a, b;
    a.h = __floats2half2_rn(v.x, v.y);
    b.h = __floats2half2_rn(v.z, v.w);
    uint2 u; u.x = a.u; u.y = b.u;
    *(reinterpret_cast<uint2*>(base + ((size_t)node << 4)) + sub) = u;
}

// xs payload: half4 (dinv*x0, dinv*x1, dinv*x2, 0) = 8 B per node
__device__ inline float3 load_xs(const __half* xs, int node) {
    uint2 u = *reinterpret_cast<const uint2*>(xs + ((size_t)node << 2));
    union { unsigned u; __half2 h; } a, b;
    a.u = u.x; b.u = u.y;
    float2 fa = __half22float2(a.h), fb = __half22float2(b.h);
    return make_float3(fa.x, fa.y, fb.x);
}

// zero gcur[NB] + scal[18]
__global__ void k_init(int* __restrict__ gcur, float* __restrict__ scal) {
    int t = threadIdx.x;
    gcur[t] = 0;
    if (t < 18) scal[t] = 0.f;
}

// LDS multisplit of edges into 256-node buckets; reserve directly in the
// fixed-capacity packed[] layout (bucket b owns [b*CAP, b*CAP+cnt)).
__global__ void __launch_bounds__(BINTH) k_bin(const int* __restrict__ row,
                                               const int* __restrict__ col,
                                               int* __restrict__ gcur,
                                               int* __restrict__ packed, int E) {
    __shared__ int stage[EB];
    __shared__ unsigned short sbuk[EB];
    __shared__ int hist[NB];
    __shared__ int lscan[NB];
    __shared__ int cur[NB];
    __shared__ int gbase[NB];
    int tid = threadIdx.x;
    int base = blockIdx.x * EB;
    int cnt = min(EB, E - base);

    if (tid < NB) hist[tid] = 0;
    __syncthreads();
    for (int j = tid; j < cnt; j += BINTH) {
        int c = __builtin_nontemporal_load(col + base + j);
        atomicAdd(&hist[c >> BSH], 1);
    }
    __syncthreads();
    if (tid < NB) lscan[tid] = hist[tid];
    __syncthreads();
    for (int d = 1; d < NB; d <<= 1) {
        int t = (tid < NB && tid >= d) ? lscan[tid - d] : 0;
        __syncthreads();
        if (tid < NB && tid >= d) lscan[tid] += t;
        __syncthreads();
    }
    if (tid < NB) {
        int ex = lscan[tid] - hist[tid];
        lscan[tid] = ex;
        cur[tid] = ex;
    }
    __syncthreads();
    for (int j = tid; j < cnt; j += BINTH) {
        int c = __builtin_nontemporal_load(col + base + j);
        int r = __builtin_nontemporal_load(row + base + j);
        int b = c >> BSH;
        int p = atomicAdd(&cur[b], 1);
        stage[p] = (r << BSH) | (c & ((1 << BSH) - 1));
        sbuk[p] = (unsigned short)b;
    }
    __syncthreads();
    if (tid < NB && hist[tid] > 0)
        gbase[tid] = tid * CAP + atomicAdd(&gcur[tid], hist[tid]);
    __syncthreads();
    for (int j = tid; j < cnt; j += BINTH) {
        int b = sbuk[j];
        int pos = gbase[b] + (j - lscan[b]);
        packed[pos] = stage[j];
    }
}

// per-bucket: degree hist + scan of PADDED(x8) lengths -> degi/offs/dinv/xs,
// dummy-pad fill, then fine placement into srcs (capacity layout, x8-aligned).
__global__ void __launch_bounds__(BLK) k_place(const int* __restrict__ packed,
                                               const int* __restrict__ bcnt,
                                               const float* __restrict__ x,
                                               int* __restrict__ degi,
                                               int* __restrict__ offs,
                                               float* __restrict__ dinv,
                                               __half* __restrict__ xs,
                                               int* __restrict__ srcs, int n) {
    __shared__ int cnt[256];
    __shared__ int lcur[256];
    __shared__ int ssum[256];
    int tid = threadIdx.x;
    int b = blockIdx.x;
    int nb0 = b << BSH;
    cnt[tid] = 0;
    __syncthreads();
    int ecnt = bcnt[b];
    const int* pk = packed + (size_t)b * CAP;
    for (int j = tid; j < ecnt; j += BLK)
        atomicAdd(&cnt[pk[j] & 255], 1);
    __syncthreads();
    int c = cnt[tid];
    int pl = (c + 7) & ~7;                 // padded length (x8)
    ssum[tid] = pl;
    __syncthreads();
    for (int d = 1; d < 256; d <<= 1) {
        int t = (tid >= d) ? ssum[tid - d] : 0;
        __syncthreads();
        if (tid >= d) ssum[tid] += t;
        __syncthreads();
    }
    int A = b * SCAP + (ssum[tid] - pl);   // absolute aligned base for node
    lcur[tid] = A;
    int valid = min(n - nb0, 256);
    int i = nb0 + tid;
    if (tid < valid) {
        degi[i] = pl;
        offs[i] = A;
        float di = rsqrtf((float)c + 2.0f);
        dinv[i] = di;
        float x0 = x[i * 3 + 0], x1 = x[i * 3 + 1], x2 = x[i * 3 + 2];
        union { unsigned u; __half2 h; } a2, b2;
        a2.h = __floats2half2_rn(di * x0, di * x1);
        b2.h = __floats2half2_rn(di * x2, 0.f);
        uint2 u; u.x = a2.u; u.y = b2.u;
        *reinterpret_cast<uint2*>(xs + ((size_t)i << 2)) = u;
        for (int k = c; k < pl; k++) srcs[A + k] = n;   // dummy pads
    }
    if (b == 0 && tid == 0) {              // zero the dummy xs payload
        uint2 z; z.x = 0u; z.y = 0u;
        *reinterpret_cast<uint2*>(xs + ((size_t)n << 2)) = z;
    }
    __syncthreads();
    for (int j = tid; j < ecnt; j += BLK) {
        int v = pk[j];
        int li = v & 255;
        int slot = atomicAdd(&lcur[li], 1);
        srcs[slot] = v >> BSH;
    }
}

// layer-1: DUAL-NODE rank-3 aggregation of xs, then @W1+relu, @W2 -> hwsB.
__global__ void __launch_bounds__(BLK) k_agg1(const __half* __restrict__ xs,
                                              const int* __restrict__ offs,
                                              const int* __restrict__ degi,
                                              const int* __restrict__ srcs,
                                              const float* __restrict__ dinv,
                                              const float* __restrict__ b1,
                                              const float* __restrict__ W1,
                                              const float* __restrict__ W2,
                                              __half* __restrict__ hwsB, int n) {
    __shared__ float w1[48];
    __shared__ float w2[256];
    __shared__ float bb[16];
    __shared__ float hbuf[128][17];
    int tid = threadIdx.x;
    w2[tid] = W2[tid];
    if (tid < 48) w1[tid] = W1[tid];
    if (tid < 16) bb[tid] = b1[tid];
    if (blockIdx.x == 0 && tid < 8)        // zero the dummy hwsB payload (32 B)
        reinterpret_cast<unsigned*>(hwsB + ((size_t)n << 4))[tid] = 0u;
    __syncthreads();
    int nl = tid >> 2, sub = tid & 3;
    int iA = blockIdx.x * 128 + nl;
    int iB = iA + 64;
    bool actA = (iA < n), actB = (iB < n);
    int AA = actA ? offs[iA] : 0;
    int AB = actB ? offs[iB] : 0;
    int plA = actA ? degi[iA] : 0;
    int plB = actB ? degi[iB] : 0;
    float axA = 0.f, ayA = 0.f, azA = 0.f;
    float axB = 0.f, ayB = 0.f, azB = 0.f;
    int plM = max(plA, plB);
    for (int j = 4 * sub; j < plM; j += 16) {
        int ja = min(j, max(plA - 4, 0));
        int jb = min(j, max(plB - 4, 0));
        int4 sa = *reinterpret_cast<const int4*>(srcs + AA + ja);
        int4 sb = *reinterpret_cast<const int4*>(srcs + AB + jb);
        if (j >= plA) sa = make_int4(n, n, n, n);
        if (j >= plB) sb = make_int4(n, n, n, n);
        float3 qa0 = load_xs(xs, sa.x);
        float3 qa1 = load_xs(xs, sa.y);
        float3 qa2 = load_xs(xs, sa.z);
        float3 qa3 = load_xs(xs, sa.w);
        float3 qb0 = load_xs(xs, sb.x);
        float3 qb1 = load_xs(xs, sb.y);
        float3 qb2 = load_xs(xs, sb.z);
        float3 qb3 = load_xs(xs, sb.w);
        axA += qa0.x + qa1.x + qa2.x + qa3.x;
        ayA += qa0.y + qa1.y + qa2.y + qa3.y;
        azA += qa0.z + qa1.z + qa2.z + qa3.z;
        axB += qb0.x + qb1.x + qb2.x + qb3.x;
        ayB += qb0.y + qb1.y + qb2.y + qb3.y;
        azB += qb0.z + qb1.z + qb2.z + qb3.z;
    }
    axA += __shfl_xor(axA, 1); ayA += __shfl_xor(ayA, 1); azA += __shfl_xor(azA, 1);
    axA += __shfl_xor(axA, 2); ayA += __shfl_xor(ayA, 2); azA += __shfl_xor(azA, 2);
    axB += __shfl_xor(axB, 1); ayB += __shfl_xor(ayB, 1); azB += __shfl_xor(azB, 1);
    axB += __shfl_xor(axB, 2); ayB += __shfl_xor(ayB, 2); azB += __shfl_xor(azB, 2);
    float diA = 0.f, diB = 0.f;
    if (actA) {
        diA = dinv[iA];
        float3 s = load_xs(xs, iA);
        float ax = axA + 2.f * s.x, ay = ayA + 2.f * s.y, az = azA + 2.f * s.z;
#pragma unroll
        for (int k = 0; k < 4; k++) {
            int f = sub * 4 + k;
            float hv = diA * (ax * w1[f] + ay * w1[16 + f] + az * w1[32 + f]) + bb[f];
            hbuf[nl][f] = fmaxf(hv, 0.f);
        }
    }
    if (actB) {
        diB = dinv[iB];
        float3 s = load_xs(xs, iB);
        float ax = axB + 2.f * s.x, ay = ayB + 2.f * s.y, az = azB + 2.f * s.z;
#pragma unroll
        for (int k = 0; k < 4; k++) {
            int f = sub * 4 + k;
            float hv = diB * (ax * w1[f] + ay * w1[16 + f] + az * w1[32 + f]) + bb[f];
            hbuf[64 + nl][f] = fmaxf(hv, 0.f);
        }
    }
    __syncthreads();
    if (actA) {
        const float* hn = hbuf[nl];
        float s0 = 0.f, s1 = 0.f, s2 = 0.f, s3 = 0.f;
#pragma unroll
        for (int f = 0; f < 16; f++) {
            float hv = hn[f];
            const float4 wq = *(const float4*)&w2[f * 16 + sub * 4];
            s0 += hv * wq.x; s1 += hv * wq.y; s2 += hv * wq.z; s3 += hv * wq.w;
        }
        store_h4(hwsB, iA, sub, make_float4(diA * s0, diA * s1, diA * s2, diA * s3));
    }
    if (actB) {
        const float* hn = hbuf[64 + nl];
        float s0 = 0.f, s1 = 0.f, s2 = 0.f, s3 = 0.f;
#pragma unroll
        for (int f = 0; f < 16; f++) {
            float hv = hn[f];
            const float4 wq = *(const float4*)&w2[f * 16 + sub * 4];
            s0 += hv * wq.x; s1 += hv * wq.y; s2 += hv * wq.z; s3 += hv * wq.w;
        }
        store_h4(hwsB, iB, sub, make_float4(diB * s0, diB * s1, diB * s2, diB * s3));
    }
}

// layer-2: 2-LANE/NODE dual-node gather (16B/lane/edge, 2 addr/edge) + relu
// + pool + layer-3 transform. Lane sub in {0,1} owns features [sub*8,sub*8+8).
__global__ void __launch_bounds__(AGB) k_agg2(const __half* __restrict__ hwsB,
                                              const int* __restrict__ offs,
                                              const int* __restrict__ degi,
                                              const int* __restrict__ srcs,
                                              const float* __restrict__ dinv,
                                              const float* __restrict__ b2,
                                              const float* __restrict__ W3,
                                              float* __restrict__ hws3,
                                              float* __restrict__ pool, int n) {
    __shared__ float w3[16];
    __shared__ float bb[16];
    __shared__ float lp[16];
    int tid = threadIdx.x;
    if (tid < 16) { w3[tid] = W3[tid]; bb[tid] = b2[tid]; lp[tid] = 0.f; }
    if (blockIdx.x == 0 && tid == 0) hws3[n] = 0.f;   // zero dummy hws3
    __syncthreads();
    int nl = tid >> 1, sub = tid & 1;
    int iA = blockIdx.x * 128 + nl;
    int iB = iA + 64;
    bool actA = (iA < n), actB = (iB < n);
    float diA = actA ? dinv[iA] : 0.f;
    float diB = actB ? dinv[iB] : 0.f;
    int AA = actA ? offs[iA] : 0;
    int AB = actB ? offs[iB] : 0;
    int plA = actA ? degi[iA] : 0;
    int plB = actB ? degi[iB] : 0;
    float4 z4 = make_float4(0.f, 0.f, 0.f, 0.f);
    float4 sAlo = z4, sAhi = z4, sBlo = z4, sBhi = z4;
    if (actA) load_h8(hwsB, iA, sub, sAlo, sAhi);
    if (actB) load_h8(hwsB, iB, sub, sBlo, sBhi);
    float4 aLo0 = make_float4(2.f * sAlo.x, 2.f * sAlo.y, 2.f * sAlo.z, 2.f * sAlo.w);
    float4 aHi0 = make_float4(2.f * sAhi.x, 2.f * sAhi.y, 2.f * sAhi.z, 2.f * sAhi.w);
    float4 bLo0 = make_float4(2.f * sBlo.x, 2.f * sBlo.y, 2.f * sBlo.z, 2.f * sBlo.w);
    float4 bHi0 = make_float4(2.f * sBhi.x, 2.f * sBhi.y, 2.f * sBhi.z, 2.f * sBhi.w);
    float4 aLo1 = z4, aHi1 = z4, bLo1 = z4, bHi1 = z4;
    int plM = max(plA, plB);
    for (int j = 0; j < plM; j += 4) {
        int ja = min(j, max(plA - 4, 0));
        int jb = min(j, max(plB - 4, 0));
        int4 sa = *reinterpret_cast<const int4*>(srcs + AA + ja);
        int4 sb = *reinterpret_cast<const int4*>(srcs + AB + jb);
        if (j >= plA) sa = make_int4(n, n, n, n);
        if (j >= plB) sb = make_int4(n, n, n, n);
        float4 qa0l, qa0h, qa1l, qa1h, qa2l, qa2h, qa3l, qa3h;
        float4 qb0l, qb0h, qb1l, qb1h, qb2l, qb2h, qb3l, qb3h;
        load_h8(hwsB, sa.x, sub, qa0l, qa0h);
        load_h8(hwsB, sa.y, sub, qa1l, qa1h);
        load_h8(hwsB, sa.z, sub, qa2l, qa2h);
        load_h8(hwsB, sa.w, sub, qa3l, qa3h);
        load_h8(hwsB, sb.x, sub, qb0l, qb0h);
        load_h8(hwsB, sb.y, sub, qb1l, qb1h);
        load_h8(hwsB, sb.z, sub, qb2l, qb2h);
        load_h8(hwsB, sb.w, sub, qb3l, qb3h);
        aLo0.x += qa0l.x + qa2l.x; aLo0.y += qa0l.y + qa2l.y;
        aLo0.z += qa0l.z + qa2l.z; aLo0.w += qa0l.w + qa2l.w;
        aLo1.x += qa1l.x + qa3l.x; aLo1.y += qa1l.y + qa3l.y;
        aLo1.z += qa1l.z + qa3l.z; aLo1.w += qa1l.w + qa3l.w;
        aHi0.x += qa0h.x + qa2h.x; aHi0.y += qa0h.y + qa2h.y;
        aHi0.z += qa0h.z + qa2h.z; aHi0.w += qa0h.w + qa2h.w;
        aHi1.x += qa1h.x + qa3h.x; aHi1.y += qa1h.y + qa3h.y;
        aHi1.z += qa1h.z + qa3h.z; aHi1.w += qa1h.w + qa3h.w;
        bLo0.x += qb0l.x + qb2l.x; bLo0.y += qb0l.y + qb2l.y;
        bLo0.z += qb0l.z + qb2l.z; bLo0.w += qb0l.w + qb2l.w;
        bLo1.x += qb1l.x + qb3l.x; bLo1.y += qb1l.y + qb3l.y;
        bLo1.z += qb1l.z + qb3l.z; bLo1.w += qb1l.w + qb3l.w;
        bHi0.x += qb0h.x + qb2h.x; bHi0.y += qb0h.y + qb2h.y;
        bHi0.z += qb0h.z + qb2h.z; bHi0.w += qb0h.w + qb2h.w;
        bHi1.x += qb1h.x + qb3h.x; bHi1.y += qb1h.y + qb3h.y;
        bHi1.z += qb1h.z + qb3h.z; bHi1.w += qb1h.w + qb3h.w;
    }
    aLo0.x += aLo1.x; aLo0.y += aLo1.y; aLo0.z += aLo1.z; aLo0.w += aLo1.w;
    aHi0.x += aHi1.x; aHi0.y += aHi1.y; aHi0.z += aHi1.z; aHi0.w += aHi1.w;
    bLo0.x += bLo1.x; bLo0.y += bLo1.y; bLo0.z += bLo1.z; bLo0.w += bLo1.w;
    bHi0.x += bHi1.x; bHi0.y += bHi1.y; bHi0.z += bHi1.z; bHi0.w += bHi1.w;
    int fb = sub * 8;
    float4 hAlo = z4, hAhi = z4, hBlo = z4, hBhi = z4;
    if (actA) {
        hAlo.x = fmaxf(diA * aLo0.x + bb[fb + 0], 0.f);
        hAlo.y = fmaxf(diA * aLo0.y + bb[fb + 1], 0.f);
        hAlo.z = fmaxf(diA * aLo0.z + bb[fb + 2], 0.f);
        hAlo.w = fmaxf(diA * aLo0.w + bb[fb + 3], 0.f);
        hAhi.x = fmaxf(diA * aHi0.x + bb[fb + 4], 0.f);
        hAhi.y = fmaxf(diA * aHi0.y + bb[fb + 5], 0.f);
        hAhi.z = fmaxf(diA * aHi0.z + bb[fb + 6], 0.f);
        hAhi.w = fmaxf(diA * aHi0.w + bb[fb + 7], 0.f);
    }
    if (actB) {
        hBlo.x = fmaxf(diB * bLo0.x + bb[fb + 0], 0.f);
        hBlo.y = fmaxf(diB * bLo0.y + bb[fb + 1], 0.f);
        hBlo.z = fmaxf(diB * bLo0.z + bb[fb + 2], 0.f);
        hBlo.w = fmaxf(diB * bLo0.w + bb[fb + 3], 0.f);
        hBhi.x = fmaxf(diB * bHi0.x + bb[fb + 4], 0.f);
        hBhi.y = fmaxf(diB * bHi0.y + bb[fb + 5], 0.f);
        hBhi.z = fmaxf(diB * bHi0.z + bb[fb + 6], 0.f);
        hBhi.w = fmaxf(diB * bHi0.w + bb[fb + 7], 0.f);
    }
    // layer-3 transform: dot over this lane's 8 features, combine the 2 lanes
    float pA = hAlo.x * w3[fb + 0] + hAlo.y * w3[fb + 1]
             + hAlo.z * w3[fb + 2] + hAlo.w * w3[fb + 3]
             + hAhi.x * w3[fb + 4] + hAhi.y * w3[fb + 5]
             + hAhi.z * w3[fb + 6] + hAhi.w * w3[fb + 7];
    float pB = hBlo.x * w3[fb + 0] + hBlo.y * w3[fb + 1]
             + hBlo.z * w3[fb + 2] + hBlo.w * w3[fb + 3]
             + hBhi.x * w3[fb + 4] + hBhi.y * w3[fb + 5]
             + hBhi.z * w3[fb + 6] + hBhi.w * w3[fb + 7];
    pA += __shfl_xor(pA, 1);
    pB += __shfl_xor(pB, 1);
    if (sub == 0) {
        if (actA) hws3[iA] = diA * pA;
        if (actB) hws3[iB] = diB * pB;
    }
    // pool: reduce over same-parity lanes (masks 2..32); lanes 0/1 hold totals
    float4 hplo = make_float4(hAlo.x + hBlo.x, hAlo.y + hBlo.y,
                              hAlo.z + hBlo.z, hAlo.w + hBlo.w);
    float4 hphi = make_float4(hAhi.x + hBhi.x, hAhi.y + hBhi.y,
                              hAhi.z + hBhi.z, hAhi.w + hBhi.w);
#pragma unroll
    for (int m = 2; m < 64; m <<= 1) {
        hplo.x += __shfl_xor(hplo.x, m);
        hplo.y += __shfl_xor(hplo.y, m);
        hplo.z += __shfl_xor(hplo.z, m);
        hplo.w += __shfl_xor(hplo.w, m);
        hphi.x += __shfl_xor(hphi.x, m);
        hphi.y += __shfl_xor(hphi.y, m);
        hphi.z += __shfl_xor(hphi.z, m);
        hphi.w += __shfl_xor(hphi.w, m);
    }
    if ((tid & 63) < 2) {
        atomicAdd(&lp[fb + 0], hplo.x);
        atomicAdd(&lp[fb + 1], hplo.y);
        atomicAdd(&lp[fb + 2], hplo.z);
        atomicAdd(&lp[fb + 3], hplo.w);
        atomicAdd(&lp[fb + 4], hphi.x);
        atomicAdd(&lp[fb + 5], hphi.y);
        atomicAdd(&lp[fb + 6], hphi.z);
        atomicAdd(&lp[fb + 7], hphi.w);
    }
    __syncthreads();
    if (tid < 16) atomicAdd(&pool[tid], lp[tid]);
}

// layer-3: DUAL-NODE scalar aggregation (8-index chunks per lane, stride 32)
// -> logits; per-block (max, sum-exp) for the fused softmax.
__global__ void __launch_bounds__(BLK) k_agg3(const float* __restrict__ hws3,
                                              const int* __restrict__ offs,
                                              const int* __restrict__ degi,
                                              const int* __restrict__ srcs,
                                              const float* __restrict__ dinv,
                                              const float* __restrict__ b3,
                                              const int* __restrict__ choices,
                                              float* __restrict__ cbuf,
                                              float* __restrict__ bmax,
                                              float* __restrict__ bsum, int n) {
    __shared__ float red[BLK];
    int tid = threadIdx.x;
    int nl = tid >> 2, sub = tid & 3;
    int iA = blockIdx.x * 128 + nl;
    int iB = iA + 64;
    bool actA = (iA < n), actB = (iB < n);
    int AA = actA ? offs[iA] : 0;
    int AB = actB ? offs[iB] : 0;
    int plA = actA ? degi[iA] : 0;
    int plB = actB ? degi[iB] : 0;
    float sA0 = 0.f, sA1 = 0.f, sB0 = 0.f, sB1 = 0.f;
    int plM = max(plA, plB);
    for (int j = 8 * sub; j < plM; j += 32) {
        int ja = min(j, max(plA - 8, 0));
        int jb = min(j, max(plB - 8, 0));
        int4 sa0 = *reinterpret_cast<const int4*>(srcs + AA + ja);
        int4 sa1 = *reinterpret_cast<const int4*>(srcs + AA + ja + 4);
        int4 sb0 = *reinterpret_cast<const int4*>(srcs + AB + jb);
        int4 sb1 = *reinterpret_cast<const int4*>(srcs + AB + jb + 4);
        if (j >= plA) { sa0 = make_int4(n, n, n, n); sa1 = sa0; }
        if (j >= plB) { sb0 = make_int4(n, n, n, n); sb1 = sb0; }
        sA0 += hws3[sa0.x] + hws3[sa0.z] + hws3[sa1.x] + hws3[sa1.z];
        sA1 += hws3[sa0.y] + hws3[sa0.w] + hws3[sa1.y] + hws3[sa1.w];
        sB0 += hws3[sb0.x] + hws3[sb0.z] + hws3[sb1.x] + hws3[sb1.z];
        sB1 += hws3[sb0.y] + hws3[sb0.w] + hws3[sb1.y] + hws3[sb1.w];
    }
    float sA = sA0 + sA1, sB = sB0 + sB1;
    sA += __shfl_xor(sA, 1); sA += __shfl_xor(sA, 2);
    sB += __shfl_xor(sB, 1); sB += __shfl_xor(sB, 2);
    float lA = -INFINITY, lB = -INFINITY;
    if (sub == 0) {
        if (actA) {
            float c = dinv[iA] * (sA + 2.f * hws3[iA]) + b3[0];
            cbuf[iA] = c;
            if (choices[iA] != 0) lA = c;
        }
        if (actB) {
            float c = dinv[iB] * (sB + 2.f * hws3[iB]) + b3[0];
            cbuf[iB] = c;
            if (choices[iB] != 0) lB = c;
        }
    }
    red[tid] = fmaxf(lA, lB);
    __syncthreads();
    for (int d = BLK / 2; d > 0; d >>= 1) {
        if (tid < d) red[tid] = fmaxf(red[tid], red[tid + d]);
        __syncthreads();
    }
    float bm = red[0];
    __syncthreads();
    float es = 0.f;
    if (lA > -INFINITY) es += expf(lA - bm);
    if (lB > -INFINITY) es += expf(lB - bm);
    red[tid] = es;
    __syncthreads();
    for (int d = BLK / 2; d > 0; d >>= 1) {
        if (tid < d) red[tid] += red[tid + d];
        __syncthreads();
    }
    if (tid == 0) { bmax[blockIdx.x] = bm; bsum[blockIdx.x] = red[0]; }
}

// final: every block redundantly combines per-block (max,sum) -> (M,S),
// then writes probabilities; block 0 writes the value head.
__global__ void __launch_bounds__(BLK) k_final(const float* __restrict__ cbuf,
                                               const int* __restrict__ choices,
                                               const float* __restrict__ bmax,
                                               const float* __restrict__ bsum,
                                               const float* __restrict__ pool,
                                               const float* __restrict__ fcw,
                                               const float* __restrict__ fcb,
                                               float* __restrict__ out,
                                               int nblk, int n) {
    __shared__ float red[BLK];
    __shared__ float MS[2];
    int tid = threadIdx.x;
    float m = -INFINITY;
    for (int i = tid; i < nblk; i += BLK) m = fmaxf(m, bmax[i]);
    red[tid] = m;
    __syncthreads();
    for (int d = BLK / 2; d > 0; d >>= 1) {
        if (tid < d) red[tid] = fmaxf(red[tid], red[tid + d]);
        __syncthreads();
    }
    float M = red[0];
    __syncthreads();
    float s = 0.f;
    for (int i = tid; i < nblk; i += BLK) {
        float bm = bmax[i];
        if (bm > -INFINITY) s += bsum[i] * expf(bm - M);
    }
    red[tid] = s;
    __syncthreads();
    for (int d = BLK / 2; d > 0; d >>= 1) {
        if (tid < d) red[tid] += red[tid + d];
        __syncthreads();
    }
    if (tid == 0) { MS[0] = M; MS[1] = red[0]; }
    __syncthreads();
    float Mv = MS[0], Sv = MS[1];
    int i = blockIdx.x * BLK + tid;
    if (i < n) {
        float p = 0.0f;
        if (choices[i] != 0) p = expf(cbuf[i] - Mv) / Sv;
        out[i] = p;
    }
    if (blockIdx.x == 0 && tid == 0) {
        float invn = 1.0f / (float)n;
        float v = 0.0f;
#pragma unroll
        for (int f = 0; f < 16; f++) v += (pool[f] * invn) * fcw[f];
        out[n] = v + fcb[0];
    }
}

extern "C" void kernel_launch(void* const* d_in, const int* in_sizes, int n_in,
                              void* d_out, int out_size, void* d_ws, size_t ws_size,
                              hipStream_t stream) {
    const float* x       = (const float*)d_in[0];
    const int*   ei      = (const int*)d_in[1];
    const int*   choices = (const int*)d_in[2];
    const float* W1 = (const float*)d_in[3];
    const float* b1 = (const float*)d_in[4];
    const float* W2 = (const float*)d_in[5];
    const float* b2 = (const float*)d_in[6];
    const float* W3 = (const float*)d_in[7];
    const float* b3 = (const float*)d_in[8];
    const float* fcw = (const float*)d_in[9];
    const float* fcb = (const float*)d_in[10];
    float* out = (float*)d_out;

    int n = in_sizes[0] / 3;
    int E = in_sizes[1] / 2;
    const int* row = ei;
    const int* col = ei + E;

    int nblkN = (n + BLK - 1) / BLK;           // 391
    int nblk128 = (n + 127) / 128;             // 782   (dual-node kernels)
    int nbuck = (n + (1 << BSH) - 1) >> BSH;   // 391 buckets of 256 nodes
    int nblkBin = (E + EB - 1) / EB;           // 391 binning blocks

    // workspace layout (16B aligned slices); ws_size is ~268 MB, plenty
    char* ws = (char*)d_ws;
    size_t o = 0;
    auto alloc = [&](size_t bytes) { char* p = ws + o; o += (bytes + 15) & ~(size_t)15; return p; };
    int*   degi   = (int*)  alloc((size_t)n * 4);
    int*   offs   = (int*)  alloc((size_t)n * 4);
    float* dinv   = (float*)alloc((size_t)n * 4);
    float* hws3   = (float*)alloc((size_t)(n + 1) * 4);  // +1: dummy node
    float* cbuf   = (float*)alloc((size_t)n * 4);
    float* bmax   = (float*)alloc(8192);       // >= nblk128 floats
    float* bsum   = (float*)alloc(8192);
    int*   gcur   = (int*)  alloc(NB * 4);
    float* scal   = (float*)alloc(256);   // [1..16]=pool
    float* pool   = scal + 1;
    __half* xs    = (__half*)alloc((size_t)(n + 1) * 4 * 2);  // half4/node +dummy
    size_t hw_bytes = (size_t)(n + 1) * 16 * 2;          // hwsB (fp16) + dummy
    size_t pk_bytes = (size_t)NB * CAP * 4;              // packed (capacity layout)
    char*  blob   = alloc(hw_bytes > pk_bytes ? hw_bytes : pk_bytes);
    int*    packed = (int*)blob;          // build phase only; dead before k_agg1
    __half* hwsB   = (__half*)blob;
    int*   srcs   = (int*)  alloc((size_t)NB * SCAP * 4);    // capacity layout
    (void)ws_size;  // ~65 MB used

    // ---- build (2 passes over edges; no per-edge global atomics) ----
    k_init<<<1, NB, 0, stream>>>(gcur, scal);
    k_bin<<<nblkBin, BINTH, 0, stream>>>(row, col, gcur, packed, E);
    k_place<<<nbuck, BLK, 0, stream>>>(packed, gcur, x, degi, offs, dinv, xs, srcs, n);

    // ---- GCN layers ----
    k_agg1<<<nblk128, BLK, 0, stream>>>(xs, offs, degi, srcs, dinv, b1, W1, W2, hwsB, n);
    k_agg2<<<nblk128, AGB, 0, stream>>>(hwsB, offs, degi, srcs, dinv, b2, W3, hws3, pool, n);
    k_agg3<<<nblk128, BLK, 0, stream>>>(hws3, offs, degi, srcs, dinv, b3, choices, cbuf, bmax, bsum, n);

    // ---- softmax combine fused into final ----
    k_final<<<nblkN, BLK, 0, stream>>>(cbuf, choices, bmax, bsum, pool, fcw, fcb, out, nblk128, n);
}

// Round 15
// 223.653 us; speedup vs baseline: 1.0317x; 1.0317x over previous
//
#include <hip/hip_runtime.h>
#include <hip/hip_fp16.h>
#include <math.h>

#define BLK 256

// ---------------------------------------------------------------------------
// GCNPolicyNetwork: 3-layer improved-GCN + masked softmax + mean-pool value.
// Round 15: REVERT to R13 (best known, 222.98 us). R14's address-halving test
// regressed (231 us) -> gathers are latency-bound with saturated MLP, not
// address-throughput-bound. Lever audit complete: working set (R5), MLP
// (R9/R12/R13), balance (R10 neg), addresses (R14 neg), edge-centric (R7 neg),
// build atomics (R3/R9/R11). This is the converged structure.
// ---------------------------------------------------------------------------

#define BSH 8                    // 256 nodes per bucket
#define NB 512                   // bucket-array size (nbuck=391 <= 512)
#define CAP 10240                // packed[] capacity per bucket (mean ~8184)
#define SCAP 12288               // srcs[] capacity per bucket (CAP + 8*256 pad)
#define EB 8192                  // edges per binning block
#define BINTH 1024               // k_bin block size

// ---- fp16 payload helpers ----
__device__ inline float4 load_h4(const __half* base, int node, int sub) {
    const uint2* p = reinterpret_cast<const uint2*>(base + ((size_t)node << 4)) + sub;
    uint2 u = *p;
    union { unsigned u; __half2 h; } a, b;
    a.u = u.x; b.u = u.y;
    float2 fa = __half22float2(a.h), fb = __half22float2(b.h);
    return make_float4(fa.x, fa.y, fb.x, fb.y);
}

__device__ inline void store_h4(__half* base, int node, int sub, float4 v) {
    union { unsigned u; __half2 h; } a, b;
    a.h = __floats2half2_rn(v.x, v.y);
    b.h = __floats2half2_rn(v.z, v.w);
    uint2 u; u.x = a.u; u.y = b.u;
    *(reinterpret_cast<uint2*>(base + ((size_t)node << 4)) + sub) = u;
}

// xs payload: half4 (dinv*x0, dinv*x1, dinv*x2, 0) = 8 B per node
__device__ inline float3 load_xs(const __half* xs, int node) {
    uint2 u = *reinterpret_cast<const uint2*>(xs + ((size_t)node << 2));
    union { unsigned u; __half2 h; } a, b;
    a.u = u.x; b.u = u.y;
    float2 fa = __half22float2(a.h), fb = __half22float2(b.h);
    return make_float3(fa.x, fa.y, fb.x);
}

// zero gcur[NB] + scal[18]
__global__ void k_init(int* __restrict__ gcur, float* __restrict__ scal) {
    int t = threadIdx.x;
    gcur[t] = 0;
    if (t < 18) scal[t] = 0.f;
}

// LDS multisplit of edges into 256-node buckets; reserve directly in the
// fixed-capacity packed[] layout (bucket b owns [b*CAP, b*CAP+cnt)).
__global__ void __launch_bounds__(BINTH) k_bin(const int* __restrict__ row,
                                               const int* __restrict__ col,
                                               int* __restrict__ gcur,
                                               int* __restrict__ packed, int E) {
    __shared__ int stage[EB];
    __shared__ unsigned short sbuk[EB];
    __shared__ int hist[NB];
    __shared__ int lscan[NB];
    __shared__ int cur[NB];
    __shared__ int gbase[NB];
    int tid = threadIdx.x;
    int base = blockIdx.x * EB;
    int cnt = min(EB, E - base);

    if (tid < NB) hist[tid] = 0;
    __syncthreads();
    for (int j = tid; j < cnt; j += BINTH) {
        int c = __builtin_nontemporal_load(col + base + j);
        atomicAdd(&hist[c >> BSH], 1);
    }
    __syncthreads();
    if (tid < NB) lscan[tid] = hist[tid];
    __syncthreads();
    for (int d = 1; d < NB; d <<= 1) {
        int t = (tid < NB && tid >= d) ? lscan[tid - d] : 0;
        __syncthreads();
        if (tid < NB && tid >= d) lscan[tid] += t;
        __syncthreads();
    }
    if (tid < NB) {
        int ex = lscan[tid] - hist[tid];
        lscan[tid] = ex;
        cur[tid] = ex;
    }
    __syncthreads();
    for (int j = tid; j < cnt; j += BINTH) {
        int c = __builtin_nontemporal_load(col + base + j);
        int r = __builtin_nontemporal_load(row + base + j);
        int b = c >> BSH;
        int p = atomicAdd(&cur[b], 1);
        stage[p] = (r << BSH) | (c & ((1 << BSH) - 1));
        sbuk[p] = (unsigned short)b;
    }
    __syncthreads();
    if (tid < NB && hist[tid] > 0)
        gbase[tid] = tid * CAP + atomicAdd(&gcur[tid], hist[tid]);
    __syncthreads();
    for (int j = tid; j < cnt; j += BINTH) {
        int b = sbuk[j];
        int pos = gbase[b] + (j - lscan[b]);
        packed[pos] = stage[j];
    }
}

// per-bucket: degree hist + scan of PADDED(x8) lengths -> degi/offs/dinv/xs,
// dummy-pad fill, then fine placement into srcs (capacity layout, x8-aligned).
__global__ void __launch_bounds__(BLK) k_place(const int* __restrict__ packed,
                                               const int* __restrict__ bcnt,
                                               const float* __restrict__ x,
                                               int* __restrict__ degi,
                                               int* __restrict__ offs,
                                               float* __restrict__ dinv,
                                               __half* __restrict__ xs,
                                               int* __restrict__ srcs, int n) {
    __shared__ int cnt[256];
    __shared__ int lcur[256];
    __shared__ int ssum[256];
    int tid = threadIdx.x;
    int b = blockIdx.x;
    int nb0 = b << BSH;
    cnt[tid] = 0;
    __syncthreads();
    int ecnt = bcnt[b];
    const int* pk = packed + (size_t)b * CAP;
    for (int j = tid; j < ecnt; j += BLK)
        atomicAdd(&cnt[pk[j] & 255], 1);
    __syncthreads();
    int c = cnt[tid];
    int pl = (c + 7) & ~7;                 // padded length (x8)
    ssum[tid] = pl;
    __syncthreads();
    for (int d = 1; d < 256; d <<= 1) {
        int t = (tid >= d) ? ssum[tid - d] : 0;
        __syncthreads();
        if (tid >= d) ssum[tid] += t;
        __syncthreads();
    }
    int A = b * SCAP + (ssum[tid] - pl);   // absolute aligned base for node
    lcur[tid] = A;
    int valid = min(n - nb0, 256);
    int i = nb0 + tid;
    if (tid < valid) {
        degi[i] = pl;
        offs[i] = A;
        float di = rsqrtf((float)c + 2.0f);
        dinv[i] = di;
        float x0 = x[i * 3 + 0], x1 = x[i * 3 + 1], x2 = x[i * 3 + 2];
        union { unsigned u; __half2 h; } a2, b2;
        a2.h = __floats2half2_rn(di * x0, di * x1);
        b2.h = __floats2half2_rn(di * x2, 0.f);
        uint2 u; u.x = a2.u; u.y = b2.u;
        *reinterpret_cast<uint2*>(xs + ((size_t)i << 2)) = u;
        for (int k = c; k < pl; k++) srcs[A + k] = n;   // dummy pads
    }
    if (b == 0 && tid == 0) {              // zero the dummy xs payload
        uint2 z; z.x = 0u; z.y = 0u;
        *reinterpret_cast<uint2*>(xs + ((size_t)n << 2)) = z;
    }
    __syncthreads();
    for (int j = tid; j < ecnt; j += BLK) {
        int v = pk[j];
        int li = v & 255;
        int slot = atomicAdd(&lcur[li], 1);
        srcs[slot] = v >> BSH;
    }
}

// layer-1: DUAL-NODE rank-3 aggregation of xs, then @W1+relu, @W2 -> hwsB.
// Team of 4 lanes walks nodes iA and iB=iA+64 together (128 nodes/block).
__global__ void __launch_bounds__(BLK) k_agg1(const __half* __restrict__ xs,
                                              const int* __restrict__ offs,
                                              const int* __restrict__ degi,
                                              const int* __restrict__ srcs,
                                              const float* __restrict__ dinv,
                                              const float* __restrict__ b1,
                                              const float* __restrict__ W1,
                                              const float* __restrict__ W2,
                                              __half* __restrict__ hwsB, int n) {
    __shared__ float w1[48];
    __shared__ float w2[256];
    __shared__ float bb[16];
    __shared__ float hbuf[128][17];
    int tid = threadIdx.x;
    w2[tid] = W2[tid];
    if (tid < 48) w1[tid] = W1[tid];
    if (tid < 16) bb[tid] = b1[tid];
    if (blockIdx.x == 0 && tid < 8)        // zero the dummy hwsB payload (32 B)
        reinterpret_cast<unsigned*>(hwsB + ((size_t)n << 4))[tid] = 0u;
    __syncthreads();
    int nl = tid >> 2, sub = tid & 3;
    int iA = blockIdx.x * 128 + nl;
    int iB = iA + 64;
    bool actA = (iA < n), actB = (iB < n);
    int AA = actA ? offs[iA] : 0;
    int AB = actB ? offs[iB] : 0;
    int plA = actA ? degi[iA] : 0;
    int plB = actB ? degi[iB] : 0;
    float axA = 0.f, ayA = 0.f, azA = 0.f;
    float axB = 0.f, ayB = 0.f, azB = 0.f;
    int plM = max(plA, plB);
    for (int j = 4 * sub; j < plM; j += 16) {
        int ja = min(j, max(plA - 4, 0));
        int jb = min(j, max(plB - 4, 0));
        int4 sa = *reinterpret_cast<const int4*>(srcs + AA + ja);
        int4 sb = *reinterpret_cast<const int4*>(srcs + AB + jb);
        if (j >= plA) sa = make_int4(n, n, n, n);
        if (j >= plB) sb = make_int4(n, n, n, n);
        float3 qa0 = load_xs(xs, sa.x);
        float3 qa1 = load_xs(xs, sa.y);
        float3 qa2 = load_xs(xs, sa.z);
        float3 qa3 = load_xs(xs, sa.w);
        float3 qb0 = load_xs(xs, sb.x);
        float3 qb1 = load_xs(xs, sb.y);
        float3 qb2 = load_xs(xs, sb.z);
        float3 qb3 = load_xs(xs, sb.w);
        axA += qa0.x + qa1.x + qa2.x + qa3.x;
        ayA += qa0.y + qa1.y + qa2.y + qa3.y;
        azA += qa0.z + qa1.z + qa2.z + qa3.z;
        axB += qb0.x + qb1.x + qb2.x + qb3.x;
        ayB += qb0.y + qb1.y + qb2.y + qb3.y;
        azB += qb0.z + qb1.z + qb2.z + qb3.z;
    }
    axA += __shfl_xor(axA, 1); ayA += __shfl_xor(ayA, 1); azA += __shfl_xor(azA, 1);
    axA += __shfl_xor(axA, 2); ayA += __shfl_xor(ayA, 2); azA += __shfl_xor(azA, 2);
    axB += __shfl_xor(axB, 1); ayB += __shfl_xor(ayB, 1); azB += __shfl_xor(azB, 1);
    axB += __shfl_xor(axB, 2); ayB += __shfl_xor(ayB, 2); azB += __shfl_xor(azB, 2);
    float diA = 0.f, diB = 0.f;
    if (actA) {
        diA = dinv[iA];
        float3 s = load_xs(xs, iA);
        float ax = axA + 2.f * s.x, ay = ayA + 2.f * s.y, az = azA + 2.f * s.z;
#pragma unroll
        for (int k = 0; k < 4; k++) {
            int f = sub * 4 + k;
            float hv = diA * (ax * w1[f] + ay * w1[16 + f] + az * w1[32 + f]) + bb[f];
            hbuf[nl][f] = fmaxf(hv, 0.f);
        }
    }
    if (actB) {
        diB = dinv[iB];
        float3 s = load_xs(xs, iB);
        float ax = axB + 2.f * s.x, ay = ayB + 2.f * s.y, az = azB + 2.f * s.z;
#pragma unroll
        for (int k = 0; k < 4; k++) {
            int f = sub * 4 + k;
            float hv = diB * (ax * w1[f] + ay * w1[16 + f] + az * w1[32 + f]) + bb[f];
            hbuf[64 + nl][f] = fmaxf(hv, 0.f);
        }
    }
    __syncthreads();
    if (actA) {
        const float* hn = hbuf[nl];
        float s0 = 0.f, s1 = 0.f, s2 = 0.f, s3 = 0.f;
#pragma unroll
        for (int f = 0; f < 16; f++) {
            float hv = hn[f];
            const float4 wq = *(const float4*)&w2[f * 16 + sub * 4];
            s0 += hv * wq.x; s1 += hv * wq.y; s2 += hv * wq.z; s3 += hv * wq.w;
        }
        store_h4(hwsB, iA, sub, make_float4(diA * s0, diA * s1, diA * s2, diA * s3));
    }
    if (actB) {
        const float* hn = hbuf[64 + nl];
        float s0 = 0.f, s1 = 0.f, s2 = 0.f, s3 = 0.f;
#pragma unroll
        for (int f = 0; f < 16; f++) {
            float hv = hn[f];
            const float4 wq = *(const float4*)&w2[f * 16 + sub * 4];
            s0 += hv * wq.x; s1 += hv * wq.y; s2 += hv * wq.z; s3 += hv * wq.w;
        }
        store_h4(hwsB, iB, sub, make_float4(diB * s0, diB * s1, diB * s2, diB * s3));
    }
}

// layer-2: DUAL-NODE interleaved gather + relu + pool + layer-3 transform.
__global__ void __launch_bounds__(BLK) k_agg2(const __half* __restrict__ hwsB,
                                              const int* __restrict__ offs,
                                              const int* __restrict__ degi,
                                              const int* __restrict__ srcs,
                                              const float* __restrict__ dinv,
                                              const float* __restrict__ b2,
                                              const float* __restrict__ W3,
                                              float* __restrict__ hws3,
                                              float* __restrict__ pool, int n) {
    __shared__ float w3[16];
    __shared__ float bb[16];
    __shared__ float lp[16];
    int tid = threadIdx.x;
    if (tid < 16) { w3[tid] = W3[tid]; bb[tid] = b2[tid]; lp[tid] = 0.f; }
    if (blockIdx.x == 0 && tid == 0) hws3[n] = 0.f;   // zero dummy hws3
    __syncthreads();
    int nl = tid >> 2, sub = tid & 3;
    int iA = blockIdx.x * 128 + nl;
    int iB = iA + 64;
    bool actA = (iA < n), actB = (iB < n);
    float diA = actA ? dinv[iA] : 0.f;
    float diB = actB ? dinv[iB] : 0.f;
    int AA = actA ? offs[iA] : 0;
    int AB = actB ? offs[iB] : 0;
    int plA = actA ? degi[iA] : 0;
    int plB = actB ? degi[iB] : 0;
    float4 z4 = make_float4(0.f, 0.f, 0.f, 0.f);
    float4 sA = actA ? load_h4(hwsB, iA, sub) : z4;
    float4 sB = actB ? load_h4(hwsB, iB, sub) : z4;
    float4 accA = make_float4(2.f * sA.x, 2.f * sA.y, 2.f * sA.z, 2.f * sA.w);
    float4 accB = make_float4(2.f * sB.x, 2.f * sB.y, 2.f * sB.z, 2.f * sB.w);
    float4 a1A = z4, a1B = z4;
    int plM = max(plA, plB);
    for (int j = 0; j < plM; j += 8) {
        int ja = min(j, max(plA - 8, 0));
        int jb = min(j, max(plB - 8, 0));
        int4 sa0 = *reinterpret_cast<const int4*>(srcs + AA + ja);
        int4 sa1 = *reinterpret_cast<const int4*>(srcs + AA + ja + 4);
        int4 sb0 = *reinterpret_cast<const int4*>(srcs + AB + jb);
        int4 sb1 = *reinterpret_cast<const int4*>(srcs + AB + jb + 4);
        if (j >= plA) { sa0 = make_int4(n, n, n, n); sa1 = sa0; }
        if (j >= plB) { sb0 = make_int4(n, n, n, n); sb1 = sb0; }
        float4 qa0 = load_h4(hwsB, sa0.x, sub);
        float4 qa1 = load_h4(hwsB, sa0.y, sub);
        float4 qa2 = load_h4(hwsB, sa0.z, sub);
        float4 qa3 = load_h4(hwsB, sa0.w, sub);
        float4 qa4 = load_h4(hwsB, sa1.x, sub);
        float4 qa5 = load_h4(hwsB, sa1.y, sub);
        float4 qa6 = load_h4(hwsB, sa1.z, sub);
        float4 qa7 = load_h4(hwsB, sa1.w, sub);
        float4 qb0 = load_h4(hwsB, sb0.x, sub);
        float4 qb1 = load_h4(hwsB, sb0.y, sub);
        float4 qb2 = load_h4(hwsB, sb0.z, sub);
        float4 qb3 = load_h4(hwsB, sb0.w, sub);
        float4 qb4 = load_h4(hwsB, sb1.x, sub);
        float4 qb5 = load_h4(hwsB, sb1.y, sub);
        float4 qb6 = load_h4(hwsB, sb1.z, sub);
        float4 qb7 = load_h4(hwsB, sb1.w, sub);
        accA.x += qa0.x + qa2.x + qa4.x + qa6.x;
        accA.y += qa0.y + qa2.y + qa4.y + qa6.y;
        accA.z += qa0.z + qa2.z + qa4.z + qa6.z;
        accA.w += qa0.w + qa2.w + qa4.w + qa6.w;
        a1A.x += qa1.x + qa3.x + qa5.x + qa7.x;
        a1A.y += qa1.y + qa3.y + qa5.y + qa7.y;
        a1A.z += qa1.z + qa3.z + qa5.z + qa7.z;
        a1A.w += qa1.w + qa3.w + qa5.w + qa7.w;
        accB.x += qb0.x + qb2.x + qb4.x + qb6.x;
        accB.y += qb0.y + qb2.y + qb4.y + qb6.y;
        accB.z += qb0.z + qb2.z + qb4.z + qb6.z;
        accB.w += qb0.w + qb2.w + qb4.w + qb6.w;
        a1B.x += qb1.x + qb3.x + qb5.x + qb7.x;
        a1B.y += qb1.y + qb3.y + qb5.y + qb7.y;
        a1B.z += qb1.z + qb3.z + qb5.z + qb7.z;
        a1B.w += qb1.w + qb3.w + qb5.w + qb7.w;
    }
    accA.x += a1A.x; accA.y += a1A.y; accA.z += a1A.z; accA.w += a1A.w;
    accB.x += a1B.x; accB.y += a1B.y; accB.z += a1B.z; accB.w += a1B.w;
    float4 hA = z4, hB = z4;
    if (actA) {
        hA.x = fmaxf(diA * accA.x + bb[sub * 4 + 0], 0.f);
        hA.y = fmaxf(diA * accA.y + bb[sub * 4 + 1], 0.f);
        hA.z = fmaxf(diA * accA.z + bb[sub * 4 + 2], 0.f);
        hA.w = fmaxf(diA * accA.w + bb[sub * 4 + 3], 0.f);
    }
    if (actB) {
        hB.x = fmaxf(diB * accB.x + bb[sub * 4 + 0], 0.f);
        hB.y = fmaxf(diB * accB.y + bb[sub * 4 + 1], 0.f);
        hB.z = fmaxf(diB * accB.z + bb[sub * 4 + 2], 0.f);
        hB.w = fmaxf(diB * accB.w + bb[sub * 4 + 3], 0.f);
    }
    float pA = hA.x * w3[sub * 4 + 0] + hA.y * w3[sub * 4 + 1]
             + hA.z * w3[sub * 4 + 2] + hA.w * w3[sub * 4 + 3];
    float pB = hB.x * w3[sub * 4 + 0] + hB.y * w3[sub * 4 + 1]
             + hB.z * w3[sub * 4 + 2] + hB.w * w3[sub * 4 + 3];
    pA += __shfl_xor(pA, 1); pA += __shfl_xor(pA, 2);
    pB += __shfl_xor(pB, 1); pB += __shfl_xor(pB, 2);
    if (sub == 0) {
        if (actA) hws3[iA] = diA * pA;
        if (actB) hws3[iB] = diB * pB;
    }
    float4 hp = make_float4(hA.x + hB.x, hA.y + hB.y, hA.z + hB.z, hA.w + hB.w);
#pragma unroll
    for (int m = 4; m < 64; m <<= 1) {
        hp.x += __shfl_xor(hp.x, m);
        hp.y += __shfl_xor(hp.y, m);
        hp.z += __shfl_xor(hp.z, m);
        hp.w += __shfl_xor(hp.w, m);
    }
    if ((tid & 63) < 4) {
        atomicAdd(&lp[sub * 4 + 0], hp.x);
        atomicAdd(&lp[sub * 4 + 1], hp.y);
        atomicAdd(&lp[sub * 4 + 2], hp.z);
        atomicAdd(&lp[sub * 4 + 3], hp.w);
    }
    __syncthreads();
    if (tid < 16) atomicAdd(&pool[tid], lp[tid]);
}

// layer-3: DUAL-NODE scalar aggregation (8-index chunks per lane, stride 32)
// -> logits; per-block (max, sum-exp) for the fused softmax.
__global__ void __launch_bounds__(BLK) k_agg3(const float* __restrict__ hws3,
                                              const int* __restrict__ offs,
                                              const int* __restrict__ degi,
                                              const int* __restrict__ srcs,
                                              const float* __restrict__ dinv,
                                              const float* __restrict__ b3,
                                              const int* __restrict__ choices,
                                              float* __restrict__ cbuf,
                                              float* __restrict__ bmax,
                                              float* __restrict__ bsum, int n) {
    __shared__ float red[BLK];
    int tid = threadIdx.x;
    int nl = tid >> 2, sub = tid & 3;
    int iA = blockIdx.x * 128 + nl;
    int iB = iA + 64;
    bool actA = (iA < n), actB = (iB < n);
    int AA = actA ? offs[iA] : 0;
    int AB = actB ? offs[iB] : 0;
    int plA = actA ? degi[iA] : 0;
    int plB = actB ? degi[iB] : 0;
    float sA0 = 0.f, sA1 = 0.f, sB0 = 0.f, sB1 = 0.f;
    int plM = max(plA, plB);
    for (int j = 8 * sub; j < plM; j += 32) {
        int ja = min(j, max(plA - 8, 0));
        int jb = min(j, max(plB - 8, 0));
        int4 sa0 = *reinterpret_cast<const int4*>(srcs + AA + ja);
        int4 sa1 = *reinterpret_cast<const int4*>(srcs + AA + ja + 4);
        int4 sb0 = *reinterpret_cast<const int4*>(srcs + AB + jb);
        int4 sb1 = *reinterpret_cast<const int4*>(srcs + AB + jb + 4);
        if (j >= plA) { sa0 = make_int4(n, n, n, n); sa1 = sa0; }
        if (j >= plB) { sb0 = make_int4(n, n, n, n); sb1 = sb0; }
        sA0 += hws3[sa0.x] + hws3[sa0.z] + hws3[sa1.x] + hws3[sa1.z];
        sA1 += hws3[sa0.y] + hws3[sa0.w] + hws3[sa1.y] + hws3[sa1.w];
        sB0 += hws3[sb0.x] + hws3[sb0.z] + hws3[sb1.x] + hws3[sb1.z];
        sB1 += hws3[sb0.y] + hws3[sb0.w] + hws3[sb1.y] + hws3[sb1.w];
    }
    float sA = sA0 + sA1, sB = sB0 + sB1;
    sA += __shfl_xor(sA, 1); sA += __shfl_xor(sA, 2);
    sB += __shfl_xor(sB, 1); sB += __shfl_xor(sB, 2);
    float lA = -INFINITY, lB = -INFINITY;
    if (sub == 0) {
        if (actA) {
            float c = dinv[iA] * (sA + 2.f * hws3[iA]) + b3[0];
            cbuf[iA] = c;
            if (choices[iA] != 0) lA = c;
        }
        if (actB) {
            float c = dinv[iB] * (sB + 2.f * hws3[iB]) + b3[0];
            cbuf[iB] = c;
            if (choices[iB] != 0) lB = c;
        }
    }
    red[tid] = fmaxf(lA, lB);
    __syncthreads();
    for (int d = BLK / 2; d > 0; d >>= 1) {
        if (tid < d) red[tid] = fmaxf(red[tid], red[tid + d]);
        __syncthreads();
    }
    float bm = red[0];
    __syncthreads();
    float es = 0.f;
    if (lA > -INFINITY) es += expf(lA - bm);
    if (lB > -INFINITY) es += expf(lB - bm);
    red[tid] = es;
    __syncthreads();
    for (int d = BLK / 2; d > 0; d >>= 1) {
        if (tid < d) red[tid] += red[tid + d];
        __syncthreads();
    }
    if (tid == 0) { bmax[blockIdx.x] = bm; bsum[blockIdx.x] = red[0]; }
}

// final: every block redundantly combines per-block (max,sum) -> (M,S),
// then writes probabilities; block 0 writes the value head.
__global__ void __launch_bounds__(BLK) k_final(const float* __restrict__ cbuf,
                                               const int* __restrict__ choices,
                                               const float* __restrict__ bmax,
                                               const float* __restrict__ bsum,
                                               const float* __restrict__ pool,
                                               const float* __restrict__ fcw,
                                               const float* __restrict__ fcb,
                                               float* __restrict__ out,
                                               int nblk, int n) {
    __shared__ float red[BLK];
    __shared__ float MS[2];
    int tid = threadIdx.x;
    float m = -INFINITY;
    for (int i = tid; i < nblk; i += BLK) m = fmaxf(m, bmax[i]);
    red[tid] = m;
    __syncthreads();
    for (int d = BLK / 2; d > 0; d >>= 1) {
        if (tid < d) red[tid] = fmaxf(red[tid], red[tid + d]);
        __syncthreads();
    }
    float M = red[0];
    __syncthreads();
    float s = 0.f;
    for (int i = tid; i < nblk; i += BLK) {
        float bm = bmax[i];
        if (bm > -INFINITY) s += bsum[i] * expf(bm - M);
    }
    red[tid] = s;
    __syncthreads();
    for (int d = BLK / 2; d > 0; d >>= 1) {
        if (tid < d) red[tid] += red[tid + d];
        __syncthreads();
    }
    if (tid == 0) { MS[0] = M; MS[1] = red[0]; }
    __syncthreads();
    float Mv = MS[0], Sv = MS[1];
    int i = blockIdx.x * BLK + tid;
    if (i < n) {
        float p = 0.0f;
        if (choices[i] != 0) p = expf(cbuf[i] - Mv) / Sv;
        out[i] = p;
    }
    if (blockIdx.x == 0 && tid == 0) {
        float invn = 1.0f / (float)n;
        float v = 0.0f;
#pragma unroll
        for (int f = 0; f < 16; f++) v += (pool[f] * invn) * fcw[f];
        out[n] = v + fcb[0];
    }
}

extern "C" void kernel_launch(void* const* d_in, const int* in_sizes, int n_in,
                              void* d_out, int out_size, void* d_ws, size_t ws_size,
                              hipStream_t stream) {
    const float* x       = (const float*)d_in[0];
    const int*   ei      = (const int*)d_in[1];
    const int*   choices = (const int*)d_in[2];
    const float* W1 = (const float*)d_in[3];
    const float* b1 = (const float*)d_in[4];
    const float* W2 = (const float*)d_in[5];
    const float* b2 = (const float*)d_in[6];
    const float* W3 = (const float*)d_in[7];
    const float* b3 = (const float*)d_in[8];
    const float* fcw = (const float*)d_in[9];
    const float* fcb = (const float*)d_in[10];
    float* out = (float*)d_out;

    int n = in_sizes[0] / 3;
    int E = in_sizes[1] / 2;
    const int* row = ei;
    const int* col = ei + E;

    int nblkN = (n + BLK - 1) / BLK;           // 391
    int nblk128 = (n + 127) / 128;             // 782   (dual-node kernels)
    int nbuck = (n + (1 << BSH) - 1) >> BSH;   // 391 buckets of 256 nodes
    int nblkBin = (E + EB - 1) / EB;           // 391 binning blocks

    // workspace layout (16B aligned slices); ws_size is ~268 MB, plenty
    char* ws = (char*)d_ws;
    size_t o = 0;
    auto alloc = [&](size_t bytes) { char* p = ws + o; o += (bytes + 15) & ~(size_t)15; return p; };
    int*   degi   = (int*)  alloc((size_t)n * 4);
    int*   offs   = (int*)  alloc((size_t)n * 4);
    float* dinv   = (float*)alloc((size_t)n * 4);
    float* hws3   = (float*)alloc((size_t)(n + 1) * 4);  // +1: dummy node
    float* cbuf   = (float*)alloc((size_t)n * 4);
    float* bmax   = (float*)alloc(8192);       // >= nblk128 floats
    float* bsum   = (float*)alloc(8192);
    int*   gcur   = (int*)  alloc(NB * 4);
    float* scal   = (float*)alloc(256);   // [1..16]=pool
    float* pool   = scal + 1;
    __half* xs    = (__half*)alloc((size_t)(n + 1) * 4 * 2);  // half4/node +dummy
    size_t hw_bytes = (size_t)(n + 1) * 16 * 2;          // hwsB (fp16) + dummy
    size_t pk_bytes = (size_t)NB * CAP * 4;              // packed (capacity layout)
    char*  blob   = alloc(hw_bytes > pk_bytes ? hw_bytes : pk_bytes);
    int*    packed = (int*)blob;          // build phase only; dead before k_agg1
    __half* hwsB   = (__half*)blob;
    int*   srcs   = (int*)  alloc((size_t)NB * SCAP * 4);    // capacity layout
    (void)ws_size;  // ~65 MB used

    // ---- build (2 passes over edges; no per-edge global atomics) ----
    k_init<<<1, NB, 0, stream>>>(gcur, scal);
    k_bin<<<nblkBin, BINTH, 0, stream>>>(row, col, gcur, packed, E);
    k_place<<<nbuck, BLK, 0, stream>>>(packed, gcur, x, degi, offs, dinv, xs, srcs, n);

    // ---- GCN layers (all dual-node) ----
    k_agg1<<<nblk128, BLK, 0, stream>>>(xs, offs, degi, srcs, dinv, b1, W1, W2, hwsB, n);
    k_agg2<<<nblk128, BLK, 0, stream>>>(hwsB, offs, degi, srcs, dinv, b2, W3, hws3, pool, n);
    k_agg3<<<nblk128, BLK, 0, stream>>>(hws3, offs, degi, srcs, dinv, b3, choices, cbuf, bmax, bsum, n);

    // ---- softmax combine fused into final ----
    k_final<<<nblkN, BLK, 0, stream>>>(cbuf, choices, bmax, bsum, pool, fcw, fcb, out, nblk128, n);
}